// Round 4
// baseline (1918.892 us; speedup 1.0000x reference)
//
#include <hip/hip_runtime.h>
#include <hip/hip_bf16.h>
#include <math.h>

typedef __attribute__((ext_vector_type(8))) short short8;
typedef __attribute__((ext_vector_type(4))) float f32x4;
typedef __hip_bfloat16 bf16;

#define GAS(p) ((const __attribute__((address_space(1))) void*)(p))
#define LAS(p) ((__attribute__((address_space(3))) void*)(p))

__device__ __forceinline__ float gelu_exact(float x) {
    return 0.5f * x * (1.0f + erff(x * 0.70710678118654752f));
}
__device__ __forceinline__ float softplus_f(float x) {
    return (x > 20.f) ? x : log1pf(__expf(x));
}

// ---------------------------------------------------------------------------
// Transpose f32 (R,C) -> bf16 (C,R), out ld = R.
// ---------------------------------------------------------------------------
__global__ void transpose_to_bf16(const float* __restrict__ in, bf16* __restrict__ out,
                                  int R, int C) {
    __shared__ float tile[32][33];
    int c0 = blockIdx.x * 32, r0 = blockIdx.y * 32;
    for (int i = threadIdx.y; i < 32; i += 8) {
        int r = r0 + i, c = c0 + threadIdx.x;
        tile[i][threadIdx.x] = (r < R && c < C) ? in[(size_t)r * C + c] : 0.f;
    }
    __syncthreads();
    for (int i = threadIdx.y; i < 32; i += 8) {
        int c = c0 + i, r = r0 + threadIdx.x;
        if (c < C && r < R) out[(size_t)c * R + r] = __float2bfloat16(tile[threadIdx.x][i]);
    }
}

// ---------------------------------------------------------------------------
// Centroids + hilbert key. One wave per (b,k) row of attn (1024 elems).
// ---------------------------------------------------------------------------
__global__ void centroid_kernel(const float* __restrict__ attn, float* __restrict__ out_cent,
                                int* __restrict__ hd) {
    int row = blockIdx.x * 4 + (threadIdx.x >> 6);
    int lane = threadIdx.x & 63;
    const float* ap = attn + (size_t)row * 1024;
    float s = 0.f, sx = 0.f, sy = 0.f;
    for (int i = lane; i < 1024; i += 64) {
        float a = ap[i];
        float cxn = (float)(i & 31) * (1.0f / 31.0f);
        float cyn = (float)(i >> 5) * (1.0f / 31.0f);
        s += a; sx += a * cxn; sy += a * cyn;
    }
#pragma unroll
    for (int o = 32; o; o >>= 1) {
        s += __shfl_xor(s, o); sx += __shfl_xor(sx, o); sy += __shfl_xor(sy, o);
    }
    if (lane == 0) {
        float inv = 1.0f / (s + 1e-8f);
        float cx = sx * inv, cy = sy * inv;
        out_cent[row * 2] = cx;
        out_cent[row * 2 + 1] = cy;
        int x = (int)fminf(fmaxf(cx * 15.f, 0.f), 15.f);
        int y = (int)fminf(fmaxf(cy * 15.f, 0.f), 15.f);
        int d = 0;
        for (int s2 = 8; s2 > 0; s2 >>= 1) {
            int rx = (x & s2) ? 1 : 0, ry = (y & s2) ? 1 : 0;
            d += s2 * s2 * ((3 * rx) ^ ry);
            int x1 = rx ? (s2 - 1 - x) : x;
            int y1 = rx ? (s2 - 1 - y) : y;
            int xn = (ry == 0) ? y1 : x;
            int yn = (ry == 0) ? x1 : y;
            x = xn; y = yn;
        }
        hd[row] = d;
    }
}

// Stable argsort of 128 keys per batch. order[rank]=k.
__global__ void order_kernel(const int* __restrict__ hd, int* __restrict__ order) {
    __shared__ int dsh[128];
    int b = blockIdx.x, tid = threadIdx.x;
    dsh[tid] = hd[b * 128 + tid];
    __syncthreads();
    int mine = dsh[tid], rank = 0;
    for (int j = 0; j < 128; ++j) {
        int dj = dsh[j];
        rank += (dj < mine) || (dj == mine && j < tid);
    }
    order[b * 128 + rank] = tid;
}

// enc (8192,256) bf16: feats=[cx,cy,0.1,0.1], c = f*64 + s; s<32: sin, else cos
__global__ void enc_kernel(const float* __restrict__ cent, bf16* __restrict__ enc) {
    int row = blockIdx.x, tid = threadIdx.x;
    int f = tid >> 6, s = tid & 63;
    float feat = (f == 0) ? cent[row * 2] : (f == 1) ? cent[row * 2 + 1] : 0.1f;
    int i = s & 31;
    float freq = powf(10000.f, -(float)i * (1.f / 32.f));
    float ang = feat * freq * 3.14159f;
    float v = (s < 32) ? sinf(ang) : cosf(ang);
    enc[(size_t)row * 256 + tid] = __float2bfloat16(v);
}

// ---------------------------------------------------------------------------
// MFMA GEMM: C(8192 x N) = A(8192 x K, bf16, lda) @ Bt(N x K, bf16)^T
// 128x128 tile, BK=64, 4 waves (2x2 of 64x64), global_load_lds + XOR swizzle.
// EPI: 0 gelu->bf16 | 1 +bias+resid->f32+bf16 | 2 u/dt/BC (softplus on dt) |
//      3 +bias->bf16 | 4 +bias+resid->f32 | 5 ffn out (resid,mask,f32+bf16)
// ---------------------------------------------------------------------------
template <int EPI>
__launch_bounds__(256)
__global__ void gemm_bt(const bf16* __restrict__ A, int lda,
                        const bf16* __restrict__ Bt, int K, int ldc,
                        float* __restrict__ outF, bf16* __restrict__ outB,
                        const float* __restrict__ bias1, const float* __restrict__ bias2,
                        const float* __restrict__ resid, const float* __restrict__ mask) {
    __shared__ __align__(16) short a_sh[128 * 64];
    __shared__ __align__(16) short b_sh[128 * 64];
    const int tid = threadIdx.x;
    const int lane = tid & 63;
    const int wid = tid >> 6;
    const int wr = wid >> 1, wc = wid & 1;
    const int row0 = blockIdx.y * 128;
    const int col0 = blockIdx.x * 128;

    f32x4 acc[4][4] = {};

    const int nk = K >> 6;
    for (int kt = 0; kt < nk; ++kt) {
        __syncthreads();
#pragma unroll
        for (int c = 0; c < 4; ++c) {
            int slot = c * 256 + tid;
            int r = slot >> 3;
            int ks = (slot & 7) ^ (r & 7);
            const bf16* ga = A + (size_t)(row0 + r) * lda + (kt << 6) + (ks << 3);
            __builtin_amdgcn_global_load_lds(GAS(ga), LAS((char*)a_sh + slot * 16), 16, 0, 0);
            const bf16* gb = Bt + (size_t)(col0 + r) * K + (kt << 6) + (ks << 3);
            __builtin_amdgcn_global_load_lds(GAS(gb), LAS((char*)b_sh + slot * 16), 16, 0, 0);
        }
        __syncthreads();
#pragma unroll
        for (int kk = 0; kk < 2; ++kk) {
            short8 af[4], bfr[4];
            int kb = (kk << 2) + (lane >> 4);
#pragma unroll
            for (int m = 0; m < 4; ++m) {
                int r = wr * 64 + m * 16 + (lane & 15);
                af[m] = *(const short8*)(a_sh + ((r << 3) + (kb ^ (r & 7))) * 8);
            }
#pragma unroll
            for (int n = 0; n < 4; ++n) {
                int r = wc * 64 + n * 16 + (lane & 15);
                bfr[n] = *(const short8*)(b_sh + ((r << 3) + (kb ^ (r & 7))) * 8);
            }
#pragma unroll
            for (int m = 0; m < 4; ++m)
#pragma unroll
                for (int n = 0; n < 4; ++n)
                    acc[m][n] = __builtin_amdgcn_mfma_f32_16x16x32_bf16(af[m], bfr[n], acc[m][n], 0, 0, 0);
        }
    }

#pragma unroll
    for (int m = 0; m < 4; ++m) {
#pragma unroll
        for (int n = 0; n < 4; ++n) {
#pragma unroll
            for (int q = 0; q < 4; ++q) {
                int r = row0 + wr * 64 + m * 16 + ((lane >> 4) << 2) + q;
                int c = col0 + wc * 64 + n * 16 + (lane & 15);
                float v = acc[m][n][q];
                size_t idx = (size_t)r * ldc + c;
                if constexpr (EPI == 0) {
                    v = gelu_exact(v + bias1[c]);
                    outB[idx] = __float2bfloat16(v);
                } else if constexpr (EPI == 1) {
                    v += bias1[c] + resid[idx];
                    outF[idx] = v;
                    outB[idx] = __float2bfloat16(v);
                } else if constexpr (EPI == 2) {
                    if (c < 1024) {
                        outF[idx] = v + bias1[c];
                    } else if (c < 2048) {
                        outF[idx] = softplus_f(v + bias2[c - 1024]);
                    } else if (c < 2080) {
                        outF[idx] = v;
                    }
                } else if constexpr (EPI == 3) {
                    outB[idx] = __float2bfloat16(v + bias1[c]);
                } else if constexpr (EPI == 4) {
                    outF[idx] = v + bias1[c] + resid[(size_t)r * 1024 + c];
                } else {
                    float sv = resid[idx] + v + bias1[c];
                    sv *= mask[r];
                    outF[idx] = sv;
                    outB[idx] = __float2bfloat16(sv);
                }
            }
        }
    }
}

// ---------------------------------------------------------------------------
// Selective scan, one direction. grid (4, 64), 256 thr. Thread owns (b,d),
// h[16] in registers. Walks positions in hilbert order (dir0 ascending,
// dir1 descending), writes y at the ORIGINAL position (fuses order/flip/
// unorder). udt row layout: [u(1024) | dt(1024) | B(16) C(16) | pad], ld 2176.
// ---------------------------------------------------------------------------
__launch_bounds__(256)
__global__ void scan_kernel(const float* __restrict__ udt, const int* __restrict__ order,
                            const float* __restrict__ A_log, const float* __restrict__ Dsk,
                            bf16* __restrict__ ycat, int layer, int dir) {
    __shared__ float bc_sh[128 * 32];
    __shared__ int ord_sh[128];
    const int tid = threadIdx.x;
    const int dch = blockIdx.x, b = blockIdx.y;
    if (tid < 128) ord_sh[tid] = order[b * 128 + tid];
    __syncthreads();
    for (int i = tid; i < 128 * 32; i += 256) {
        int t = i >> 5, n = i & 31;
        int p = ord_sh[t];
        bc_sh[i] = udt[(size_t)(b * 128 + p) * 2176 + 2048 + n];
    }
    __syncthreads();
    const int d = dch * 256 + tid;
    float a[16], h[16];
    const float* al = A_log + ((size_t)((dir * 2 + layer) * 1024 + d)) * 16;
#pragma unroll
    for (int n = 0; n < 16; ++n) { a[n] = -__expf(al[n]); h[n] = 0.f; }
    const float dsk = Dsk[(dir * 2 + layer) * 1024 + d];

    float uf[4], df[4];
#pragma unroll
    for (int j = 0; j < 4; ++j) {
        int t = dir ? (127 - j) : j;
        size_t rb = (size_t)(b * 128 + ord_sh[t]) * 2176;
        uf[j] = udt[rb + d];
        df[j] = udt[rb + 1024 + d];
    }
    for (int s0 = 0; s0 < 128; s0 += 4) {
#pragma unroll
        for (int j = 0; j < 4; ++j) {
            int s = s0 + j;
            int t = dir ? (127 - s) : s;
            float u = uf[j], dt = df[j];
            int s2 = s + 4;
            if (s2 < 128) {
                int t2 = dir ? (127 - s2) : s2;
                size_t rb2 = (size_t)(b * 128 + ord_sh[t2]) * 2176;
                uf[j] = udt[rb2 + d];
                df[j] = udt[rb2 + 1024 + d];
            }
            float y = dsk * u;
            float dtu = dt * u;
#pragma unroll
            for (int n = 0; n < 16; ++n) {
                h[n] = __expf(dt * a[n]) * h[n] + dtu * bc_sh[t * 32 + n];
                y += h[n] * bc_sh[t * 32 + 16 + n];
            }
            ycat[(size_t)(b * 128 + ord_sh[t]) * 2048 + dir * 1024 + d] = __float2bfloat16(y);
        }
    }
}

// Double LayerNorm: tmp -> slots(f32) via (g1,b1), then -> h(bf16) via (g2,b2)
__launch_bounds__(256)
__global__ void ln2_kernel(const float* __restrict__ tmp, float* __restrict__ slots,
                           bf16* __restrict__ hout,
                           const float* __restrict__ g1, const float* __restrict__ b1,
                           const float* __restrict__ g2, const float* __restrict__ b2) {
    __shared__ float red[16];
    const int tid = threadIdx.x, row = blockIdx.x;
    const int lane = tid & 63, wid = tid >> 6;
    const float4 x = ((const float4*)(tmp + (size_t)row * 1024))[tid];
    float s = x.x + x.y + x.z + x.w;
    float ss = x.x * x.x + x.y * x.y + x.z * x.z + x.w * x.w;
#pragma unroll
    for (int o = 32; o; o >>= 1) { s += __shfl_xor(s, o); ss += __shfl_xor(ss, o); }
    if (lane == 0) { red[wid] = s; red[4 + wid] = ss; }
    __syncthreads();
    float S = red[0] + red[1] + red[2] + red[3];
    float SS = red[4] + red[5] + red[6] + red[7];
    float m = S * (1.f / 1024.f);
    float inv = rsqrtf(SS * (1.f / 1024.f) - m * m + 1e-5f);
    int c = tid * 4;
    float4 sv;
    sv.x = (x.x - m) * inv * g1[c] + b1[c];
    sv.y = (x.y - m) * inv * g1[c + 1] + b1[c + 1];
    sv.z = (x.z - m) * inv * g1[c + 2] + b1[c + 2];
    sv.w = (x.w - m) * inv * g1[c + 3] + b1[c + 3];
    ((float4*)(slots + (size_t)row * 1024))[tid] = sv;
    float s2 = sv.x + sv.y + sv.z + sv.w;
    float ss2 = sv.x * sv.x + sv.y * sv.y + sv.z * sv.z + sv.w * sv.w;
#pragma unroll
    for (int o = 32; o; o >>= 1) { s2 += __shfl_xor(s2, o); ss2 += __shfl_xor(ss2, o); }
    if (lane == 0) { red[8 + wid] = s2; red[12 + wid] = ss2; }
    __syncthreads();
    float S2 = red[8] + red[9] + red[10] + red[11];
    float SS2 = red[12] + red[13] + red[14] + red[15];
    float m2 = S2 * (1.f / 1024.f);
    float inv2 = rsqrtf(SS2 * (1.f / 1024.f) - m2 * m2 + 1e-5f);
    size_t ob = (size_t)row * 1024 + c;
    hout[ob]     = __float2bfloat16((sv.x - m2) * inv2 * g2[c] + b2[c]);
    hout[ob + 1] = __float2bfloat16((sv.y - m2) * inv2 * g2[c + 1] + b2[c + 1]);
    hout[ob + 2] = __float2bfloat16((sv.z - m2) * inv2 * g2[c + 2] + b2[c + 2]);
    hout[ob + 3] = __float2bfloat16((sv.w - m2) * inv2 * g2[c + 3] + b2[c + 3]);
}

// ---------------------------------------------------------------------------
static void launch_gemm(int epi, int N, hipStream_t st, const bf16* A, int lda,
                        const bf16* Bt, int K, int ldc, float* outF, bf16* outB,
                        const float* b1, const float* b2, const float* resid,
                        const float* mask) {
    dim3 grid(N / 128, 64);
    switch (epi) {
        case 0: gemm_bt<0><<<grid, 256, 0, st>>>(A, lda, Bt, K, ldc, outF, outB, b1, b2, resid, mask); break;
        case 1: gemm_bt<1><<<grid, 256, 0, st>>>(A, lda, Bt, K, ldc, outF, outB, b1, b2, resid, mask); break;
        case 2: gemm_bt<2><<<grid, 256, 0, st>>>(A, lda, Bt, K, ldc, outF, outB, b1, b2, resid, mask); break;
        case 3: gemm_bt<3><<<grid, 256, 0, st>>>(A, lda, Bt, K, ldc, outF, outB, b1, b2, resid, mask); break;
        case 4: gemm_bt<4><<<grid, 256, 0, st>>>(A, lda, Bt, K, ldc, outF, outB, b1, b2, resid, mask); break;
        default: gemm_bt<5><<<grid, 256, 0, st>>>(A, lda, Bt, K, ldc, outF, outB, b1, b2, resid, mask); break;
    }
}

static void launch_tr(hipStream_t st, const float* in, bf16* out, int R, int C) {
    dim3 g((C + 31) / 32, (R + 31) / 32);
    transpose_to_bf16<<<g, dim3(32, 8), 0, st>>>(in, out, R, C);
}

extern "C" void kernel_launch(void* const* d_in, const int* in_sizes, int n_in,
                              void* d_out, int out_size, void* d_ws, size_t ws_size,
                              hipStream_t stream) {
    (void)in_sizes; (void)n_in; (void)out_size;
    const float* slots_in = (const float*)d_in[0];
    const float* keep     = (const float*)d_in[1];
    const float* attn     = (const float*)d_in[2];
    const float* pos_W1   = (const float*)d_in[5];
    const float* pos_b1   = (const float*)d_in[6];
    const float* pos_W2   = (const float*)d_in[7];
    const float* pos_b2   = (const float*)d_in[8];
    const float* W_in     = (const float*)d_in[9];
    const float* b_in     = (const float*)d_in[10];
    const float* W_dt     = (const float*)d_in[11];
    const float* b_dt     = (const float*)d_in[12];
    const float* W_B      = (const float*)d_in[13];
    const float* W_C      = (const float*)d_in[14];
    const float* A_log    = (const float*)d_in[15];
    const float* Dsk      = (const float*)d_in[16];
    const float* W_out    = (const float*)d_in[17];
    const float* b_out    = (const float*)d_in[18];
    const float* merge_W  = (const float*)d_in[19];
    const float* merge_b  = (const float*)d_in[20];
    const float* norm_g   = (const float*)d_in[21];
    const float* norm_b   = (const float*)d_in[22];
    const float* ffn_lng  = (const float*)d_in[23];
    const float* ffn_lnb  = (const float*)d_in[24];
    const float* ffn_W1   = (const float*)d_in[25];
    const float* ffn_b1   = (const float*)d_in[26];
    const float* ffn_W2   = (const float*)d_in[27];
    const float* ffn_b2   = (const float*)d_in[28];

    float* out_slots = (float*)d_out;
    float* out_cent  = out_slots + (size_t)8192 * 1024;

    // ---- workspace layout (~130 MB total) ----
    char* ws = (char*)d_ws;
    size_t off = 0;
    auto alloc = [&](size_t bytes) -> char* {
        char* r = ws + off;
        off += (bytes + 255) & ~(size_t)255;
        return r;
    };
    bf16* wpool    = (bf16*)alloc((size_t)4096 * 1024 * 2);   // 8 MB JIT weight pool
    bf16* slots_bf = (bf16*)alloc((size_t)8192 * 1024 * 2);   // 16 MB
    int*  hd       = (int*)alloc((size_t)8192 * 4);
    int*  order    = (int*)alloc((size_t)8192 * 4);
    char* scratch  = alloc((size_t)104857600);                // 100 MB phase pool
    if (ws_size < off) return;  // diagnostic guard: fails absmax (not crash) if ws too small

    // scratch phase windows
    float* udt  = (float*)scratch;                       // 8192*2176*4 = 68 MB
    bf16*  ycat = (bf16*)(scratch + 71303168);           // 32 MB, ends at 100 MB
    bf16*  encb = (bf16*)scratch;                        // 4 MB   (pos phase)
    bf16*  h1   = (bf16*)(scratch + 4194304);            // 16 MB  (pos phase)
    bf16*  fbwd = (bf16*)scratch;                        // 32 MB  (post-scan)
    float* tmp  = (float*)(scratch + 33554432);          // 32 MB  [32,64)
    bf16*  hbuf = (bf16*)(scratch + 71303168);           // 16 MB  (ycat region, post-GEMM3)
    bf16*  mid  = (bf16*)scratch;                        // 64 MB  (FFN phase)

    // ---- centroids, hilbert order, positional encoding ----
    centroid_kernel<<<2048, 256, 0, stream>>>(attn, out_cent, hd);
    order_kernel<<<64, 128, 0, stream>>>(hd, order);
    enc_kernel<<<8192, 256, 0, stream>>>(out_cent, encb);

    // pos MLP: h1 = gelu(enc@W1+b1); slots = slots_in + h1@W2 + b2
    bf16* posW1t = wpool;                  // (1024,256)
    bf16* posW2t = wpool + 262144;         // (1024,1024)
    launch_tr(stream, pos_W1, posW1t, 256, 1024);
    launch_tr(stream, pos_W2, posW2t, 1024, 1024);
    launch_gemm(0, 1024, stream, encb, 256, posW1t, 256, 1024, nullptr, h1,
                pos_b1, nullptr, nullptr, nullptr);
    launch_gemm(1, 1024, stream, h1, 1024, posW2t, 1024, 1024, out_slots, slots_bf,
                pos_b2, nullptr, slots_in, nullptr);

    for (int l = 0; l < 2; ++l) {
        // ---- u/dt/B/C + selective scan, per direction ----
        for (int dir = 0; dir < 2; ++dir) {
            size_t wsl = (size_t)(dir * 2 + l);
            launch_tr(stream, W_in + wsl * 1048576, wpool, 1024, 1024);
            launch_tr(stream, W_dt + wsl * 1048576, wpool + (size_t)1024 * 1024, 1024, 1024);
            launch_tr(stream, W_B + wsl * 16384, wpool + (size_t)2048 * 1024, 1024, 16);
            launch_tr(stream, W_C + wsl * 16384, wpool + (size_t)2064 * 1024, 1024, 16);
            // rows 2080-2175 of wpool are garbage; EPI2 never stores those columns.
            launch_gemm(2, 2176, stream, slots_bf, 1024, wpool, 1024, 2176, udt, nullptr,
                        b_in + wsl * 1024, b_dt + wsl * 1024, nullptr, nullptr);
            scan_kernel<<<dim3(4, 64), 256, 0, stream>>>(udt, order, A_log, Dsk, ycat, l, dir);
        }
        // ---- per-direction output projections -> fbwd halves (ld 2048) ----
        for (int dir = 0; dir < 2; ++dir) {
            size_t wsl = (size_t)(dir * 2 + l);
            launch_tr(stream, W_out + wsl * 1048576, wpool, 1024, 1024);
            launch_gemm(3, 1024, stream, ycat + dir * 1024, 2048, wpool, 1024, 2048,
                        nullptr, fbwd + dir * 1024, b_out + wsl * 1024, nullptr, nullptr, nullptr);
        }
        // ---- merge + residual -> tmp ----
        launch_tr(stream, merge_W + (size_t)l * 2097152, wpool, 2048, 1024);
        launch_gemm(4, 1024, stream, fbwd, 2048, wpool, 2048, 1024, tmp, nullptr,
                    merge_b + l * 1024, nullptr, out_slots, nullptr);
        // ---- LN -> slots(f32); LN2 -> hbuf(bf16) ----
        ln2_kernel<<<8192, 256, 0, stream>>>(tmp, out_slots, hbuf,
                                             norm_g + l * 1024, norm_b + l * 1024,
                                             ffn_lng + l * 1024, ffn_lnb + l * 1024);
        // ---- FFN ----
        launch_tr(stream, ffn_W1 + (size_t)l * 4194304, wpool, 1024, 4096);
        launch_gemm(0, 4096, stream, hbuf, 1024, wpool, 1024, 4096, nullptr, mid,
                    ffn_b1 + (size_t)l * 4096, nullptr, nullptr, nullptr);
        launch_tr(stream, ffn_W2 + (size_t)l * 4194304, wpool, 4096, 1024);
        launch_gemm(5, 1024, stream, mid, 4096, wpool, 4096, 1024, out_slots, slots_bf,
                    ffn_b2 + l * 1024, nullptr, out_slots, keep);
    }
}